// Round 1
// baseline (615.157 us; speedup 1.0000x reference)
//
#include <hip/hip_runtime.h>
#include <math.h>

#define BB 8
#define TT 200
#define UU 100
#define U1 101
#define VV 512

// ---------------------------------------------------------------------------
// Kernel 1: per-row log-softmax stats over V=512.
// One wave (64 lanes) per (b,t,u) row. Each lane loads 2 x float4 (8 floats).
// Produces blank_lp[b,t,u] = lp[...,0] and emit_lp[b,t,u] = lp[..., label[b,u]].
// Memory-bound: reads all 330 MB of acts exactly once.
// ---------------------------------------------------------------------------
__global__ __launch_bounds__(256) void row_lse_kernel(
    const float* __restrict__ acts, const int* __restrict__ labels,
    float* __restrict__ blank_lp, float* __restrict__ emit_lp)
{
    const int wave = (blockIdx.x << 2) | ((int)threadIdx.x >> 6);
    const int lane = threadIdx.x & 63;
    const int nrows = BB * TT * U1;
    if (wave >= nrows) return;

    const float* row = acts + (size_t)wave * VV;
    float4 a = ((const float4*)row)[lane];        // elems [lane*4, lane*4+4)
    float4 c = ((const float4*)row)[lane + 64];   // elems [256+lane*4, ...)

    float m = fmaxf(fmaxf(fmaxf(a.x, a.y), fmaxf(a.z, a.w)),
                    fmaxf(fmaxf(c.x, c.y), fmaxf(c.z, c.w)));
    #pragma unroll
    for (int off = 32; off; off >>= 1)
        m = fmaxf(m, __shfl_xor(m, off, 64));

    float s = __expf(a.x - m) + __expf(a.y - m) + __expf(a.z - m) + __expf(a.w - m)
            + __expf(c.x - m) + __expf(c.y - m) + __expf(c.z - m) + __expf(c.w - m);
    #pragma unroll
    for (int off = 32; off; off >>= 1)
        s += __shfl_xor(s, off, 64);

    const float denom = m + __logf(s);

    const int u  = wave % U1;
    const int bt = wave / U1;   // = b*TT + t
    const int b  = bt / TT;

    // blank logit x[0] lives in lane 0's a.x
    float x0 = __shfl(a.x, 0, 64);
    if (lane == 0) blank_lp[wave] = x0 - denom;

    if (u < UU) {
        int lbl = labels[b * UU + u];       // wave-uniform
        int e   = lbl & 3;
        int src = (lbl >> 2) & 63;
        float4 s4 = (lbl < 256) ? a : c;
        float cand = (e == 0) ? s4.x : (e == 1) ? s4.y : (e == 2) ? s4.z : s4.w;
        float xl = __shfl(cand, src, 64);
        if (lane == 0) emit_lp[bt * UU + u] = xl - denom;
    }
}

// ---------------------------------------------------------------------------
// Kernel 2: anti-diagonal alpha recursion, one block per batch element.
// alpha[t,u] = logaddexp(alpha[t-1,u] + blank[t-1,u], alpha[t,u-1] + emit[t,u-1])
// Ping-pong LDS diagonals, one barrier per diagonal, 1-deep register prefetch
// of the blank/emit values needed next diagonal to hide global-load latency.
// ---------------------------------------------------------------------------
__global__ __launch_bounds__(128) void alpha_kernel(
    const float* __restrict__ blank_lp, const float* __restrict__ emit_lp,
    const int* __restrict__ act_lens, const int* __restrict__ label_lens,
    float* __restrict__ costs)
{
    const int b = blockIdx.x;
    const int u = threadIdx.x;
    const float* bl = blank_lp + b * TT * U1;
    const float* em = emit_lp  + b * TT * UU;
    const int Tb = act_lens[b];
    const int Ub = label_lens[b];
    const int dstar = (Tb - 1) + Ub;

    __shared__ float diag[2][U1];
    __shared__ float result;

    if (u == 0) diag[0][0] = 0.0f;   // alpha[0,0] = 0
    __syncthreads();

    const int D = (TT - 1) + UU;     // last diagonal index

    // prefetch blank/emit for d = 1
    float bl_c = 0.f, em_c = 0.f;
    {
        int t = 1 - u;
        if (u <= UU && t >= 0 && t <= TT - 1) {
            if (t >= 1) bl_c = bl[(t - 1) * U1 + u];
            if (u >= 1) em_c = em[t * UU + (u - 1)];
        }
    }

    for (int d = 1; d <= D; ++d) {
        // issue loads for diagonal d+1 early (latency overlapped with compute+barrier)
        float bl_n = 0.f, em_n = 0.f;
        {
            int t2 = (d + 1) - u;
            if (u <= UU && t2 >= 0 && t2 <= TT - 1) {
                if (t2 >= 1) bl_n = bl[(t2 - 1) * U1 + u];
                if (u >= 1)  em_n = em[t2 * UU + (u - 1)];
            }
        }

        const float* prev = diag[(d - 1) & 1];
        float*       cur  = diag[d & 1];
        int t = d - u;
        if (u <= UU && t >= 0 && t <= TT - 1) {
            float v = -INFINITY, h = -INFINITY;
            if (t >= 1) v = prev[u]     + bl_c;   // vertical: from (t-1, u)
            if (u >= 1) h = prev[u - 1] + em_c;   // horizontal: from (t, u-1)
            float mx = fmaxf(v, h);
            float mn = fminf(v, h);
            float r = mx + log1pf(__expf(mn - mx)); // exp(-inf)=0 -> r=mx at edges
            cur[u] = r;
            if (d == dstar && u == Ub) result = r;
        }
        __syncthreads();
        bl_c = bl_n; em_c = em_n;
    }

    if (u == 0) costs[b] = -(result + bl[(Tb - 1) * U1 + Ub]);
}

// ---------------------------------------------------------------------------
// Kernel 3: final sum over batch. d_out is re-poisoned before every timed
// launch, so it must be written unconditionally here.
// ---------------------------------------------------------------------------
__global__ void sum_kernel(const float* __restrict__ costs, float* __restrict__ out)
{
    if (threadIdx.x == 0) {
        float s = 0.f;
        #pragma unroll
        for (int b = 0; b < BB; ++b) s += costs[b];
        out[0] = s;
    }
}

extern "C" void kernel_launch(void* const* d_in, const int* in_sizes, int n_in,
                              void* d_out, int out_size, void* d_ws, size_t ws_size,
                              hipStream_t stream) {
    const float* acts       = (const float*)d_in[0];
    const int*   labels     = (const int*)d_in[1];
    const int*   act_lens   = (const int*)d_in[2];
    const int*   label_lens = (const int*)d_in[3];
    float* out = (float*)d_out;

    float* blank_lp = (float*)d_ws;                       // B*T*U1 floats
    float* emit_lp  = blank_lp + BB * TT * U1;            // B*T*U floats
    float* costs    = emit_lp  + BB * TT * UU;            // B floats

    const int nrows = BB * TT * U1;                       // 161600
    const int blocks1 = (nrows + 3) / 4;                  // 4 waves/block

    row_lse_kernel<<<blocks1, 256, 0, stream>>>(acts, labels, blank_lp, emit_lp);
    alpha_kernel<<<BB, 128, 0, stream>>>(blank_lp, emit_lp, act_lens, label_lens, costs);
    sum_kernel<<<1, 64, 0, stream>>>(costs, out);
}

// Round 2
// 609.323 us; speedup vs baseline: 1.0096x; 1.0096x over previous
//
#include <hip/hip_runtime.h>
#include <math.h>

#define BB 8
#define TT 200
#define UU 100
#define U1 101
#define VV 512
#define PS 102   // padded row stride (floats) for blank/emit rows: 102*4 B = 8 B aligned

// ---------------------------------------------------------------------------
// logaddexp, -inf-safe:  lae(-inf,-inf) = -inf  (fminf eats the NaN from inf-inf)
// ---------------------------------------------------------------------------
__device__ __forceinline__ float lae(float x, float y) {
    float mx = fmaxf(x, y);
    float mn = fminf(x, y);
    float d  = fminf(mn - mx, 0.0f);        // NaN -> 0; else d <= 0
    return mx + __logf(1.0f + __expf(d));   // mx = -inf  =>  -inf
}

// ---------------------------------------------------------------------------
// Kernel 1: per-row log-softmax stats over V=512.
// One wave per (b,t,u) row; 2 x float4 per lane; shuffle reductions.
// Writes blank_lp / emit_lp with padded row stride PS, zeroing the padding so
// the alpha kernel can do unguarded float2 loads.
// ---------------------------------------------------------------------------
__global__ __launch_bounds__(256) void row_lse_kernel(
    const float* __restrict__ acts, const int* __restrict__ labels,
    float* __restrict__ blank_lp, float* __restrict__ emit_lp)
{
    const int wave = (blockIdx.x << 2) | ((int)threadIdx.x >> 6);
    const int lane = threadIdx.x & 63;
    const int nrows = BB * TT * U1;
    if (wave >= nrows) return;

    const float* row = acts + (size_t)wave * VV;
    float4 a = ((const float4*)row)[lane];
    float4 c = ((const float4*)row)[lane + 64];

    float m = fmaxf(fmaxf(fmaxf(a.x, a.y), fmaxf(a.z, a.w)),
                    fmaxf(fmaxf(c.x, c.y), fmaxf(c.z, c.w)));
    #pragma unroll
    for (int off = 32; off; off >>= 1)
        m = fmaxf(m, __shfl_xor(m, off, 64));

    float s = __expf(a.x - m) + __expf(a.y - m) + __expf(a.z - m) + __expf(a.w - m)
            + __expf(c.x - m) + __expf(c.y - m) + __expf(c.z - m) + __expf(c.w - m);
    #pragma unroll
    for (int off = 32; off; off >>= 1)
        s += __shfl_xor(s, off, 64);

    const float denom = m + __logf(s);

    const int u  = wave % U1;
    const int bt = wave / U1;   // = b*TT + t
    const int b  = bt / TT;

    float x0 = __shfl(a.x, 0, 64);          // blank logit = x[0]
    if (lane == 0) blank_lp[bt * PS + u] = x0 - denom;

    if (u < UU) {
        int lbl = labels[b * UU + u];       // wave-uniform
        int e   = lbl & 3;
        int src = (lbl >> 2) & 63;
        float4 s4 = (lbl < 256) ? a : c;
        float cand = (e == 0) ? s4.x : (e == 1) ? s4.y : (e == 2) ? s4.z : s4.w;
        float xl = __shfl(cand, src, 64);
        if (lane == 0) emit_lp[bt * PS + u] = xl - denom;
    } else {
        // u == 100 wave zeroes the padding slots of this (b,t) row
        if (lane == 0) {
            emit_lp[bt * PS + 100] = 0.0f;
            emit_lp[bt * PS + 101] = 0.0f;
            blank_lp[bt * PS + 101] = 0.0f;
        }
    }
}

// ---------------------------------------------------------------------------
// Kernel 2: row-scan alpha recursion. One wave per batch element, no LDS, no
// barriers. Lane i owns u = 2i, 2i+1 (101 valid slots over 51 lanes).
//   alpha[t,u] = C[u] + cumlogaddexp_k<=u ( alpha[t-1,k] + bl[t-1,k] - C[k] )
//   C[u] = sum_{j<u} em[t,j]   (add-scan, computed one iteration ahead)
// ---------------------------------------------------------------------------
__global__ __launch_bounds__(64) void alpha_kernel(
    const float* __restrict__ blank_lp, const float* __restrict__ emit_lp,
    const int* __restrict__ act_lens, const int* __restrict__ label_lens,
    float* __restrict__ costs)
{
    const int b    = blockIdx.x;
    const int lane = threadIdx.x;
    const float* bl = blank_lp + b * TT * PS;
    const float* em = emit_lp  + b * TT * PS;
    const int Tb = act_lens[b];
    const int Ub = label_lens[b];

    const int  u0 = lane * 2, u1 = u0 + 1;
    const bool v0 = (u0 <= UU), v1 = (u1 <= UU);
    const bool ld = (lane <= 50);            // lanes that load row data

    auto load2 = [&](const float* base) -> float2 {
        return ld ? ((const float2*)base)[lane] : make_float2(0.f, 0.f);
    };

    // inclusive add-scan of e over u (identity 0); e beyond u=100 is 0
    auto addscan = [&](float e0, float e1, float& C0, float& C1) {
        float s = e0 + e1;
        #pragma unroll
        for (int off = 1; off < 64; off <<= 1) {
            float t = __shfl_up(s, off, 64);
            if (lane >= off) s += t;
        }
        float excl = __shfl_up(s, 1, 64);
        if (lane == 0) excl = 0.f;
        C0 = excl + e0;
        C1 = C0 + e1;
    };

    // e[u] = em_row[u-1] (e[0] = 0) from the lane-local float2 of em_row
    auto make_e = [&](float2 emr, float& e0, float& e1) {
        e0 = __shfl_up(emr.y, 1, 64);
        if (lane == 0) e0 = 0.f;
        e1 = emr.x;
    };

    // ---- t = 0: alpha[0,u] = C(em row 0) ----
    float a0, a1;
    {
        float2 em0 = load2(em);
        float e0, e1;
        make_e(em0, e0, e1);
        addscan(e0, e1, a0, a1);
    }

    // ---- prologue of the software pipeline ----
    float Cc0, Cc1;                 // C for row t (current iteration)
    {
        float2 em1 = load2(em + 1 * PS);
        float e0, e1;
        make_e(em1, e0, e1);
        addscan(e0, e1, Cc0, Cc1);  // C for t = 1
    }
    float2 em_nx  = load2(em + 2 * PS);   // em row 2 (C for t=2, built in iter t=1)
    float2 bl_cur = load2(bl);            // bl row 0 (used in iter t=1)

    float res = -INFINITY;

    for (int t = 1; t < Tb; ++t) {
        // prefetch for iteration t+1
        float2 bl_nx  = load2(bl + t * PS);
        float2 em_nx2 = (t + 2 < TT) ? load2(em + (t + 2) * PS)
                                     : make_float2(0.f, 0.f);

        // C for t+1 from em_nx (independent of the alpha chain -> ILP)
        float Cn0, Cn1;
        {
            float e0, e1;
            make_e(em_nx, e0, e1);
            addscan(e0, e1, Cn0, Cn1);
        }

        // ---- alpha row t: z = alpha_prev + bl[t-1] - C;  scan;  alpha = C + scan
        float z0 = v0 ? (a0 + bl_cur.x - Cc0) : -INFINITY;
        float z1 = v1 ? (a1 + bl_cur.y - Cc1) : -INFINITY;

        float s = lae(z0, z1);
        #pragma unroll
        for (int off = 1; off < 64; off <<= 1) {
            float tv = __shfl_up(s, off, 64);
            if (lane >= off) s = lae(tv, s);
        }
        float excl = __shfl_up(s, 1, 64);
        if (lane == 0) excl = -INFINITY;
        float s0 = lae(excl, z0);
        float s1 = lae(s0, z1);

        a0 = Cc0 + s0;
        a1 = Cc1 + s1;

        if (t == Tb - 1) {
            if (v0 && u0 == Ub) res = a0;
            if (v1 && u1 == Ub) res = a1;
        }

        // shift pipeline
        bl_cur = bl_nx;
        em_nx  = em_nx2;
        Cc0 = Cn0; Cc1 = Cn1;
    }

    // broadcast res (exactly one lane holds a finite value)
    #pragma unroll
    for (int off = 32; off; off >>= 1)
        res = fmaxf(res, __shfl_xor(res, off, 64));

    if (lane == 0)
        costs[b] = -(res + bl[(Tb - 1) * PS + Ub]);
}

// ---------------------------------------------------------------------------
// Kernel 3: final sum over batch. d_out re-poisoned every launch -> must write.
// ---------------------------------------------------------------------------
__global__ void sum_kernel(const float* __restrict__ costs, float* __restrict__ out)
{
    if (threadIdx.x == 0) {
        float s = 0.f;
        #pragma unroll
        for (int b = 0; b < BB; ++b) s += costs[b];
        out[0] = s;
    }
}

extern "C" void kernel_launch(void* const* d_in, const int* in_sizes, int n_in,
                              void* d_out, int out_size, void* d_ws, size_t ws_size,
                              hipStream_t stream) {
    const float* acts       = (const float*)d_in[0];
    const int*   labels     = (const int*)d_in[1];
    const int*   act_lens   = (const int*)d_in[2];
    const int*   label_lens = (const int*)d_in[3];
    float* out = (float*)d_out;

    float* blank_lp = (float*)d_ws;                       // B*T*PS floats
    float* emit_lp  = blank_lp + BB * TT * PS;            // B*T*PS floats
    float* costs    = emit_lp  + BB * TT * PS;            // B floats

    const int nrows = BB * TT * U1;                       // 161600
    const int blocks1 = (nrows + 3) / 4;                  // 4 waves/block

    row_lse_kernel<<<blocks1, 256, 0, stream>>>(acts, labels, blank_lp, emit_lp);
    alpha_kernel<<<BB, 64, 0, stream>>>(blank_lp, emit_lp, act_lens, label_lens, costs);
    sum_kernel<<<1, 64, 0, stream>>>(costs, out);
}

// Round 4
// 493.023 us; speedup vs baseline: 1.2477x; 1.2359x over previous
//
#include <hip/hip_runtime.h>
#include <math.h>

#define BB 8
#define TT 200
#define UU 100
#define U1 101
#define VV 512
#define PS 102                      // padded row stride (floats), 8B-aligned float2 lanes
#define NEG_BIG (-1.0e30f)          // lae identity; finite so no NaN (-inf - -inf) path
#define L2E 1.4426950408889634f
#define LN2 0.6931471805599453f

// v_exp_f32 is natively 2^x; HIP has no __exp2f fast intrinsic (glibc macro clash)
__device__ __forceinline__ float exp2_fast(float x) { return __builtin_amdgcn_exp2f(x); }

// ---------------------------------------------------------------------------
// DPP helper: dst = dpp_move(src) per CTRL; lanes not written (row-mask or
// out-of-bounds with bound_ctrl=false) yield `old`.
// ---------------------------------------------------------------------------
template<int CTRL, int RM>
__device__ __forceinline__ float dppf(float old, float x) {
    return __int_as_float(__builtin_amdgcn_update_dpp(
        __float_as_int(old), __float_as_int(x), CTRL, RM, 0xF, false));
}

// base-2 logaddexp; finite-in -> finite-out (no NaN), exact when |d| large
__device__ __forceinline__ float lae2(float x, float y) {
    float d = x - y;
    float e = exp2_fast(-fabsf(d));
    return fmaxf(x, y) + __log2f(1.0f + e);
}

// 64-lane inclusive scans, rocPRIM gfx9 DPP idiom:
// row_shr 1,2,4,8 then row_bcast15 (rows 1,3) and row_bcast31 (rows 2,3).
__device__ __forceinline__ float laescan(float x) {
    x = lae2(x, dppf<0x111, 0xF>(NEG_BIG, x));
    x = lae2(x, dppf<0x112, 0xF>(NEG_BIG, x));
    x = lae2(x, dppf<0x114, 0xF>(NEG_BIG, x));
    x = lae2(x, dppf<0x118, 0xF>(NEG_BIG, x));
    x = lae2(x, dppf<0x142, 0xA>(NEG_BIG, x));
    x = lae2(x, dppf<0x143, 0xC>(NEG_BIG, x));
    return x;
}
__device__ __forceinline__ float addscan(float x) {
    x = x + dppf<0x111, 0xF>(0.0f, x);
    x = x + dppf<0x112, 0xF>(0.0f, x);
    x = x + dppf<0x114, 0xF>(0.0f, x);
    x = x + dppf<0x118, 0xF>(0.0f, x);
    x = x + dppf<0x142, 0xA>(0.0f, x);
    x = x + dppf<0x143, 0xC>(0.0f, x);
    return x;
}

// whole-wave shift right by 1 (E[i] = x[i-1], E[0] = ident): row_shr:1 plus
// row_bcast fixups for the three row boundaries, selected by precomputed masks.
__device__ __forceinline__ float wave_shr1(float x, bool c1648, bool c32) {
    float t   = dppf<0x111, 0xF>(NEG_BIG, x);   // lanes 0,16,32,48 -> ident
    float b15 = dppf<0x142, 0xA>(NEG_BIG, x);   // 16-31 := x[15], 48-63 := x[47]
    float b31 = dppf<0x143, 0x4>(NEG_BIG, x);   // 32-47 := x[31]
    float e = c1648 ? b15 : t;
    return c32 ? b31 : e;
}

// ---------------------------------------------------------------------------
// Kernel 1: per-row log-softmax over V=512, one wave per (b,t,u) row.
// Skips rows never read by the recursion (t >= Tb or u > Ub): ~43% less HBM.
// Writes base-2 log-probs. Skipped ws slots stay 0xAA-poison (finite) and
// provably only contaminate lattice columns u > Ub (prefix-causal scans).
// ---------------------------------------------------------------------------
__global__ __launch_bounds__(256) void row_lse_kernel(
    const float* __restrict__ acts, const int* __restrict__ labels,
    const int* __restrict__ act_lens, const int* __restrict__ label_lens,
    float* __restrict__ blank_lp, float* __restrict__ emit_lp)
{
    const int wave = (blockIdx.x << 2) | ((int)threadIdx.x >> 6);
    const int lane = threadIdx.x & 63;
    if (wave >= BB * TT * U1) return;

    const int u  = wave % U1;
    const int bt = wave / U1;     // b*TT + t
    const int b  = bt / TT;
    const int t  = bt % TT;
    const int Ub = label_lens[b];
    if (t >= act_lens[b] || u > Ub) return;   // dead lattice row

    const float* row = acts + (size_t)wave * VV;
    float4 a = ((const float4*)row)[lane];
    float4 c = ((const float4*)row)[lane + 64];

    float m = fmaxf(fmaxf(fmaxf(a.x, a.y), fmaxf(a.z, a.w)),
                    fmaxf(fmaxf(c.x, c.y), fmaxf(c.z, c.w)));
    #pragma unroll
    for (int off = 32; off; off >>= 1)
        m = fmaxf(m, __shfl_xor(m, off, 64));

    float s = __expf(a.x - m) + __expf(a.y - m) + __expf(a.z - m) + __expf(a.w - m)
            + __expf(c.x - m) + __expf(c.y - m) + __expf(c.z - m) + __expf(c.w - m);
    #pragma unroll
    for (int off = 32; off; off >>= 1)
        s += __shfl_xor(s, off, 64);

    const float denom = m + __logf(s);

    float x0 = __shfl(a.x, 0, 64);            // blank logit = x[0]
    if (lane == 0) blank_lp[bt * PS + u] = (x0 - denom) * L2E;

    if (u < UU) {
        int lbl = labels[b * UU + u];         // wave-uniform
        int e   = lbl & 3;
        int src = (lbl >> 2) & 63;
        float4 s4 = (lbl < 256) ? a : c;
        float cand = (e == 0) ? s4.x : (e == 1) ? s4.y : (e == 2) ? s4.z : s4.w;
        float xl = __shfl(cand, src, 64);
        if (lane == 0) emit_lp[bt * PS + u] = (xl - denom) * L2E;
    }
}

// ---------------------------------------------------------------------------
// Kernel 2: row-scan alpha recursion, one wave per batch element, all in
// base-2 logs. Lane i owns u = 2i, 2i+1.
//   alpha[t,u] = C[u] + cumlae_{k<=u}( alpha[t-1,k] + bl[t-1,k] - C[k] )
//   C[u] = prefix-sum of em[t,:]; via pair-sum scan: C1 = S - e.y, C0 = S - q.
// No LDS, no barriers, no DS-shuffles in the t-loop (DPP only).
// ---------------------------------------------------------------------------
__global__ __launch_bounds__(64) void alpha_kernel(
    const float* __restrict__ blank_lp, const float* __restrict__ emit_lp,
    const int* __restrict__ act_lens, const int* __restrict__ label_lens,
    float* __restrict__ out)
{
    const int b    = blockIdx.x;
    const int lane = threadIdx.x;
    const float* bl = blank_lp + b * TT * PS;
    const float* em = emit_lp  + b * TT * PS;
    const int Tb = act_lens[b];
    const int Ub = label_lens[b];

    const int  ll    = (lane < 50) ? lane : 50;   // lanes >50 dup lane 50 (harmless)
    const bool c1648 = (lane == 16) || (lane == 48);
    const bool c32   = (lane == 32);

    const float blfin = bl[(Tb - 1) * PS + Ub];   // preload final blank (base-2)

    auto load2 = [&](const float* base) -> float2 {
        return ((const float2*)base)[ll];
    };

    // t = 0: alpha[0,u] = C(em row 0)
    float a0, a1;
    {
        float2 e = load2(em);
        float q = e.x + e.y;
        float S = addscan(q);
        a1 = S - e.y; a0 = S - q;
    }
    // C for t = 1
    float Cc0, Cc1;
    {
        float2 e = load2(em + PS);
        float q = e.x + e.y;
        float S = addscan(q);
        Cc1 = S - e.y; Cc0 = S - q;
    }
    float2 em_nx  = load2(em + 2 * PS);   // em row 2 (-> C for t=2)
    float2 bl_cur = load2(bl);            // bl row 0

    for (int t = 1; t < Tb; ++t) {
        // prefetch for iteration t+1 (off the critical chain)
        float2 bl_nx = load2(bl + t * PS);
        float2 em_n2 = (t + 2 < TT) ? load2(em + (t + 2) * PS)
                                    : make_float2(0.f, 0.f);

        // C for t+1 from em_nx (independent of alpha chain)
        float qn  = em_nx.x + em_nx.y;
        float Sn  = addscan(qn);
        float Cn1 = Sn - em_nx.y, Cn0 = Sn - qn;

        // alpha row t
        float z0 = a0 + bl_cur.x - Cc0;
        float z1 = a1 + bl_cur.y - Cc1;
        float p  = lae2(z0, z1);
        float S  = laescan(p);
        float E  = wave_shr1(S, c1648, c32);
        float s0 = lae2(E, z0);
        float s1 = lae2(s0, z1);
        a0 = Cc0 + s0;
        a1 = Cc1 + s1;

        bl_cur = bl_nx; em_nx = em_n2; Cc0 = Cn0; Cc1 = Cn1;
    }

    // result lives in lane Ub/2, slot Ub&1
    float rsel = (Ub & 1) ? a1 : a0;
    float res  = __shfl(rsel, Ub >> 1, 64);
    if (lane == 0)
        atomicAdd(out, -(res + blfin) * LN2);
}

extern "C" void kernel_launch(void* const* d_in, const int* in_sizes, int n_in,
                              void* d_out, int out_size, void* d_ws, size_t ws_size,
                              hipStream_t stream) {
    const float* acts       = (const float*)d_in[0];
    const int*   labels     = (const int*)d_in[1];
    const int*   act_lens   = (const int*)d_in[2];
    const int*   label_lens = (const int*)d_in[3];
    float* out = (float*)d_out;

    float* blank_lp = (float*)d_ws;                 // B*T*PS floats
    float* emit_lp  = blank_lp + BB * TT * PS;      // B*T*PS floats

    const int nrows   = BB * TT * U1;               // 161600
    const int blocks1 = (nrows + 3) / 4;            // 4 waves/block

    (void)hipMemsetAsync(d_out, 0, (size_t)out_size * sizeof(float), stream);
    row_lse_kernel<<<blocks1, 256, 0, stream>>>(acts, labels, act_lens, label_lens,
                                                blank_lp, emit_lp);
    alpha_kernel<<<BB, 64, 0, stream>>>(blank_lp, emit_lp, act_lens, label_lens, out);
}